// Round 1
// baseline (72.415 us; speedup 1.0000x reference)
//
#include <hip/hip_runtime.h>

// ItemCode: PQ-coded embedding reconstruction.
//   input_ids : (256, 512) int32
//   item_codes: (1000000, 8) int32
//   centroids : (8, 256, 64) float32
//   out       : (256, 512, 512) float32
// out[b,s, m*64+j] = (input_ids[b,s]==0) ? 0 : centroids[m, clamp(item_codes[input_ids[b,s], m]), j]

#define PQ_M_ 8
#define VALS_ 256
#define SUB_ 64
#define EMB_ 512
#define NTOK_ (256 * 512)

__global__ __launch_bounds__(256) void ItemCode_kernel(
    const int* __restrict__ input_ids,
    const int* __restrict__ item_codes,
    const float* __restrict__ centroids,
    float* __restrict__ out)
{
    // one thread per output float4; 128 float4 per token
    const long total = (long)NTOK_ * (EMB_ / 4);   // 16,777,216
    const long stride = (long)gridDim.x * blockDim.x;
    const float4* __restrict__ cent4 = reinterpret_cast<const float4*>(centroids);
    float4* __restrict__ out4 = reinterpret_cast<float4*>(out);

    for (long idx = (long)blockIdx.x * blockDim.x + threadIdx.x; idx < total; idx += stride) {
        const int t    = (int)(idx >> 7);   // token index (all 64 lanes of a wave share t)
        const int e    = (int)(idx & 127);  // float4 slot within token
        const int m    = e >> 4;            // PQ sub-space (16 float4 = 64 floats each)
        const int sub4 = e & 15;            // float4 within the 64-float sub-vector

        const int id = input_ids[t];        // wave-uniform -> single broadcast load
        float4 v;
        if (id == 0) {
            v = make_float4(0.f, 0.f, 0.f, 0.f);
        } else {
            int code = item_codes[id * PQ_M_ + m];
            code = min(max(code, 0), VALS_ - 1);
            // centroids[m][code][sub4*4 .. +3]  -- 16 consecutive lanes read 256 contiguous bytes
            v = cent4[(m * VALS_ + code) * (SUB_ / 4) + sub4];
        }
        out4[idx] = v;                      // fully coalesced 16 B/lane store
    }
}

extern "C" void kernel_launch(void* const* d_in, const int* in_sizes, int n_in,
                              void* d_out, int out_size, void* d_ws, size_t ws_size,
                              hipStream_t stream) {
    const int*   input_ids  = (const int*)d_in[0];
    const int*   item_codes = (const int*)d_in[1];
    const float* centroids  = (const float*)d_in[2];
    float*       out        = (float*)d_out;

    // memory-bound: 2048 blocks x 256 threads = 32 waves/CU, grid-stride x32
    dim3 grid(2048), block(256);
    ItemCode_kernel<<<grid, block, 0, stream>>>(input_ids, item_codes, centroids, out);
}

// Round 2
// 58.816 us; speedup vs baseline: 1.2312x; 1.2312x over previous
//
#include <hip/hip_runtime.h>

// ItemCode: PQ-coded embedding reconstruction.
//   input_ids : (256, 512) int32
//   item_codes: (1000000, 8) int32
//   centroids : (8, 256, 64) float32   (row 0 of each subspace is all-zero)
//   out       : (256, 512, 512) float32
// out[b,s, m*64+j] = (input_ids[b,s]==0) ? 0 : centroids[m, min(item_codes[id, m],255), j]
// Since centroids[m][0][:] == 0.0 in the input data, pad tokens can be routed
// to code 0 and share the same gather path (branch-free).

#define PQ_M_ 8
#define VALS_ 256
#define SUB_ 64
#define NTOK_ (256 * 512)
#define TOK_PER_BLK 64
#define THREADS 256

typedef float f4 __attribute__((ext_vector_type(4)));

__global__ __launch_bounds__(THREADS) void ItemCode_kernel(
    const int* __restrict__ input_ids,
    const int* __restrict__ item_codes,
    const float* __restrict__ centroids,
    float* __restrict__ out)
{
    // Stage: precomputed centroid float4-row base index per (token, m) slot.
    __shared__ int s_cidx[TOK_PER_BLK * PQ_M_];   // 512 ints = 2 KB

    const int tok_base = blockIdx.x * TOK_PER_BLK;

    #pragma unroll
    for (int k = threadIdx.x; k < TOK_PER_BLK * PQ_M_; k += THREADS) {
        const int t  = k >> 3;          // token within block
        const int m  = k & 7;           // PQ sub-space
        const int id = input_ids[tok_base + t];   // L2-hit, 8 threads broadcast
        int code = 0;                   // pad -> centroids[m][0] == 0.0
        if (id != 0) {
            code = __builtin_nontemporal_load(&item_codes[id * PQ_M_ + m]);
            code = min(code, VALS_ - 1);
        }
        s_cidx[k] = ((m * VALS_) + code) << 4;    // base in float4 units (16 f4 per row)
    }
    __syncthreads();

    const f4* __restrict__ cent4 = reinterpret_cast<const f4*>(centroids);
    f4* __restrict__ out4 = reinterpret_cast<f4*>(out);
    const int out_base = tok_base * 128;          // float4 index (max 16.7M, fits int)

    // Stream: 64 tokens * 128 float4 = 8192 float4 per block, 32 per thread.
    // Chain per iter: LDS read -> L2-resident centroid load -> NT store.
    #pragma unroll 8
    for (int i = threadIdx.x; i < TOK_PER_BLK * 128; i += THREADS) {
        const int t   = i >> 7;         // token within block
        const int e   = i & 127;        // float4 slot within token
        const int m   = e >> 4;
        const int s4  = e & 15;
        const int ci  = s_cidx[(t << 3) | m] + s4;  // broadcast LDS read (16 lanes share)
        const f4 v = cent4[ci];
        __builtin_nontemporal_store(v, &out4[out_base + i]);
    }
}

extern "C" void kernel_launch(void* const* d_in, const int* in_sizes, int n_in,
                              void* d_out, int out_size, void* d_ws, size_t ws_size,
                              hipStream_t stream) {
    const int*   input_ids  = (const int*)d_in[0];
    const int*   item_codes = (const int*)d_in[1];
    const float* centroids  = (const float*)d_in[2];
    float*       out        = (float*)d_out;

    dim3 grid(NTOK_ / TOK_PER_BLK), block(THREADS);   // 2048 blocks x 256
    ItemCode_kernel<<<grid, block, 0, stream>>>(input_ids, item_codes, centroids, out);
}